// Round 5
// baseline (49.789 us; speedup 1.0000x reference)
//
#include <hip/hip_runtime.h>
#include <hip/hip_bf16.h>
#include <math.h>

// Gaussian upsampling, round 5: 4 independent waves / block, zero barriers.
//   prepass : enc (B,S,D) f32 -> encT (B,D,S) bf16 in d_ws (validated)
//   main    : grid = B x (T/32), 256-thread blocks; wave wid owns d-span wid*64.
//     - per-wave shfl scan -> s_c / s_nir (benign identical-value race, no barrier)
//     - k-loop: explicit B-fragment prefetch (k+1 loads issued before k's exps),
//       A-fragments (w) computed in registers, 8 MFMA per step
//     - w2 = in-lane sum of bf16-rounded w + shfl_xor(16,32)  (self-consistent)
//     - epilogue: per-wave LDS transpose slice, wave-local lgkmcnt fences only,
//       coalesced dwordx4 stores with 1/w2 + sinusoidal PE fused

typedef short  bf16x8 __attribute__((ext_vector_type(8)));
typedef float  f32x4  __attribute__((ext_vector_type(4)));
typedef int    i32x4  __attribute__((ext_vector_type(4)));
typedef unsigned short u16x8 __attribute__((ext_vector_type(8)));

#define S_FIX 256
#define D_FIX 256
#define BM 32          // t-rows per block (shared by all 4 waves)
#define BN 64          // d-cols per wave
#define STG 68         // staging stride in floats (272 B, 16B-aligned)

static __device__ __forceinline__ unsigned short f2bf(float f) {
    union { float f; unsigned u; } v; v.f = f;
    unsigned r = v.u + 0x7FFFu + ((v.u >> 16) & 1u);   // RNE
    return (unsigned short)(r >> 16);
}

// pack two f32 -> one u32 of 2x bf16 (RNE); compiler emits v_cvt_pk_bf16_f32
static __device__ __forceinline__ unsigned pack_bf2(float lo, float hi) {
    float2 v; v.x = lo; v.y = hi;
    union { __hip_bfloat162 h; unsigned u; } c;
    c.h = __float22bfloat162_rn(v);
    return c.u;
}

// ---------------- prepass: enc (B,S,D) f32 -> encT (B,D,S) bf16 ----------------
__global__ __launch_bounds__(256) void transpose_enc_bf16(
    const float* __restrict__ enc, unsigned short* __restrict__ encT)
{
    const int g  = blockIdx.x * 256 + threadIdx.x;
    const int d  = g & 255;
    const int sc = (g >> 8) & 31;
    const int b  = g >> 13;
    const int s0 = sc * 8;
    const float* p = enc + ((size_t)b << 16) + (size_t)s0 * D_FIX + d;
    u16x8 v;
    #pragma unroll
    for (int j = 0; j < 8; ++j) v[j] = f2bf(p[(size_t)j * D_FIX]);
    *(u16x8*)(encT + ((size_t)b << 16) + (size_t)d * S_FIX + s0) = v;
}

// ---------------- main: 4 independent waves per block ----------------
__global__ __launch_bounds__(256) void gauss_up_mfma(
    const float* __restrict__ dur,            // (B,S)
    const float* __restrict__ rng,            // (B,S,1)
    const unsigned short* __restrict__ encT,  // (B,D,S) bf16
    float* __restrict__ out,                  // (B,T,D)
    int T)
{
    __shared__ float s_c[S_FIX];
    __shared__ float s_nir[S_FIX];            // -1/r^2
    __shared__ __align__(16) float s_stg[4][16 * STG];

    const int tid  = threadIdx.x;
    const int lane = tid & 63;
    const int wid  = tid >> 6;
    const int l15  = lane & 15;
    const int lg   = lane >> 4;
    const int ntiles = T / BM;
    const int b    = blockIdx.x / ntiles;
    const int t0   = (blockIdx.x % ntiles) * BM;
    const int d0   = wid * BN;

    // ---- per-wave scan; each wave writes ALL 256 entries (identical values),
    //      then reads only values it wrote itself -> no barrier needed ----
    {
        f32x4 dv = *(const f32x4*)(dur + b * S_FIX + 4 * lane);
        f32x4 rg = *(const f32x4*)(rng + b * S_FIX + 4 * lane);
        float q0 = dv[0];
        float q1 = q0 + dv[1];
        float q2 = q1 + dv[2];
        float q3 = q2 + dv[3];
        float tot = q3;
        #pragma unroll
        for (int off = 1; off < 64; off <<= 1) {
            float n = __shfl_up(tot, off, 64);
            if (lane >= off) tot += n;
        }
        float excl = __shfl_up(tot, 1, 64);
        if (lane == 0) excl = 0.0f;
        f32x4 c4, n4;
        c4[0] = excl + q0 - 0.5f * dv[0];
        c4[1] = excl + q1 - 0.5f * dv[1];
        c4[2] = excl + q2 - 0.5f * dv[2];
        c4[3] = excl + q3 - 0.5f * dv[3];
        #pragma unroll
        for (int i = 0; i < 4; ++i) n4[i] = -1.0f / (rg[i] * rg[i]);
        *(f32x4*)(s_c   + 4 * lane) = c4;
        *(f32x4*)(s_nir + 4 * lane) = n4;
    }
    // wave-local ordering: s_c/s_nir writes complete before k-loop reads
    asm volatile("s_waitcnt lgkmcnt(0)" ::: "memory");

    // ---- k-loop: prefetched global B, register A, 8 MFMA per step ----
    f32x4 acc[2][4];
    #pragma unroll
    for (int m = 0; m < 2; ++m)
        #pragma unroll
        for (int n = 0; n < 4; ++n) acc[m][n] = (f32x4){0.f, 0.f, 0.f, 0.f};

    float sum0 = 0.0f, sum1 = 0.0f;
    const float tt0 = (float)(t0 + l15);
    const float tt1 = (float)(t0 + 16 + l15);
    const unsigned short* eb =
        encT + ((size_t)b << 16) + (size_t)(d0 + l15) * S_FIX + lg * 8;

    bf16x8 bcur[4];
    #pragma unroll
    for (int n = 0; n < 4; ++n)
        bcur[n] = *(const bf16x8*)(eb + (size_t)n * 16 * S_FIX);

    #pragma unroll 2
    for (int k0 = 0; k0 < S_FIX; k0 += 32) {
        // prefetch next k-step's B fragments (last iter: harmless reload of k=0)
        const int kn = (k0 + 32 < S_FIX) ? k0 + 32 : 0;
        bf16x8 bnext[4];
        #pragma unroll
        for (int n = 0; n < 4; ++n)
            bnext[n] = *(const bf16x8*)(eb + (size_t)n * 16 * S_FIX + kn);

        // broadcast LDS reads (16 lanes same addr -> conflict-free)
        f32x4 cA = *(const f32x4*)(s_c   + k0 + lg * 8);
        f32x4 cB = *(const f32x4*)(s_c   + k0 + lg * 8 + 4);
        f32x4 nA = *(const f32x4*)(s_nir + k0 + lg * 8);
        f32x4 nB = *(const f32x4*)(s_nir + k0 + lg * 8 + 4);

        i32x4 a0i, a1i;
        #pragma unroll
        for (int j2 = 0; j2 < 4; ++j2) {          // k pair = (2*j2, 2*j2+1)
            const float ca_ = (j2 < 2) ? cA[(2 * j2) & 3]     : cB[(2 * j2) & 3];
            const float cb_ = (j2 < 2) ? cA[(2 * j2 + 1) & 3] : cB[(2 * j2 + 1) & 3];
            const float na_ = (j2 < 2) ? nA[(2 * j2) & 3]     : nB[(2 * j2) & 3];
            const float nb_ = (j2 < 2) ? nA[(2 * j2 + 1) & 3] : nB[(2 * j2 + 1) & 3];
            float e0a = tt0 - ca_, e0b = tt0 - cb_;
            float e1a = tt1 - ca_, e1b = tt1 - cb_;
            unsigned p0 = pack_bf2(__expf(na_ * e0a * e0a), __expf(nb_ * e0b * e0b));
            unsigned p1 = pack_bf2(__expf(na_ * e1a * e1a), __expf(nb_ * e1b * e1b));
            a0i[j2] = (int)p0;
            a1i[j2] = (int)p1;
            sum0 += __uint_as_float(p0 << 16) + __uint_as_float(p0 & 0xFFFF0000u);
            sum1 += __uint_as_float(p1 << 16) + __uint_as_float(p1 & 0xFFFF0000u);
        }
        union { i32x4 i; bf16x8 v; } ua, ub;
        ua.i = a0i; ub.i = a1i;
        #pragma unroll
        for (int n = 0; n < 4; ++n) {
            acc[0][n] = __builtin_amdgcn_mfma_f32_16x16x32_bf16(ua.v, bcur[n], acc[0][n], 0, 0, 0);
            acc[1][n] = __builtin_amdgcn_mfma_f32_16x16x32_bf16(ub.v, bcur[n], acc[1][n], 0, 0, 0);
        }
        #pragma unroll
        for (int n = 0; n < 4; ++n) bcur[n] = bnext[n];
    }

    // ---- w2 over the 4 k-slice lanes (same l15, lg varies) ----
    sum0 += __shfl_xor(sum0, 16, 64);
    sum0 += __shfl_xor(sum0, 32, 64);
    sum1 += __shfl_xor(sum1, 16, 64);
    sum1 += __shfl_xor(sum1, 32, 64);
    const float inv0 = 1.0f / (sum0 + 1e-20f);   // row l15      (m=0)
    const float inv1 = 1.0f / (sum1 + 1e-20f);   // row 16+l15   (m=1)

    // ---- epilogue: per-wave LDS transpose + PE + coalesced stores ----
    float* stg = s_stg[wid];
    const float kf  = -logf(10000.0f) / (float)D_FIX;
    const float fr0 = __expf(kf * (float)(d0 + 4 * l15));       // even col
    const float fr2 = __expf(kf * (float)(d0 + 4 * l15 + 2));
    float* ob = out + (size_t)b * T * D_FIX + (size_t)t0 * D_FIX + d0;

    #pragma unroll
    for (int m = 0; m < 2; ++m) {
        // wave-local WAR fence: prior stg reads drained before overwrite
        asm volatile("s_waitcnt lgkmcnt(0)" ::: "memory");
        #pragma unroll
        for (int n = 0; n < 4; ++n)
            #pragma unroll
            for (int r = 0; r < 4; ++r)
                stg[(lg * 4 + r) * STG + n * 16 + l15] = acc[m][n][r];
        asm volatile("s_waitcnt lgkmcnt(0)" ::: "memory");
        const float invm = m ? inv1 : inv0;
        #pragma unroll
        for (int i = 0; i < 4; ++i) {
            const int rr = 4 * i + lg;                    // row-local 0..15
            f32x4 v = *(const f32x4*)(stg + rr * STG + 4 * l15);
            const float iv = __shfl(invm, rr, 64);        // lane rr holds row rr
            const float t  = (float)(t0 + m * 16 + rr);
            float sa, ca2, sb, cb2;
            __sincosf(t * fr0, &sa, &ca2);
            __sincosf(t * fr2, &sb, &cb2);
            v[0] = v[0] * iv + sa;
            v[1] = v[1] * iv + ca2;
            v[2] = v[2] * iv + sb;
            v[3] = v[3] * iv + cb2;
            *(f32x4*)(ob + (size_t)(m * 16 + rr) * D_FIX + 4 * l15) = v;
        }
    }
}

// ---------------- fallback (round-1 f32 kernel, used if ws too small) ----------------
#define FBM 32
#define BLOCK 256
__global__ __launch_bounds__(BLOCK) void gauss_up_f32(
    const float* __restrict__ enc, const float* __restrict__ dur,
    const float* __restrict__ rng, float* __restrict__ out,
    int T, int D, int ntiles)
{
    __shared__ float s_w[FBM][S_FIX];
    __shared__ float s_c[S_FIX];
    __shared__ float s_ir2[S_FIX];
    __shared__ float s_scan[S_FIX];
    __shared__ float s_part[8][FBM];
    __shared__ float s_winv[FBM];

    const int tid = threadIdx.x;
    const int b   = blockIdx.x / ntiles;
    const int t0  = (blockIdx.x % ntiles) * FBM;

    float dv = dur[b * S_FIX + tid];
    s_scan[tid] = dv;
    __syncthreads();
    #pragma unroll
    for (int off = 1; off < S_FIX; off <<= 1) {
        float cur = s_scan[tid];
        float add = (tid >= off) ? s_scan[tid - off] : 0.0f;
        __syncthreads();
        s_scan[tid] = cur + add;
        __syncthreads();
    }
    {
        float e = s_scan[tid];
        float c = e - 0.5f * dv;
        float r = rng[b * S_FIX + tid];
        s_c[tid] = c; s_ir2[tid] = 1.0f / (r * r);
    }
    __syncthreads();
    {
        float cc = s_c[tid], ir = s_ir2[tid];
        #pragma unroll 4
        for (int tl = 0; tl < FBM; ++tl) {
            float tt = (float)(t0 + tl);
            float df = tt - cc;
            s_w[tl][tid] = __expf(-ir * df * df);
        }
    }
    __syncthreads();
    {
        const int t = tid & 31, ch = tid >> 5;
        float ps = 0.0f;
        #pragma unroll 8
        for (int j = 0; j < 32; ++j) ps += s_w[t][ch * 32 + ((j + t) & 31)];
        s_part[ch][t] = ps;
    }
    __syncthreads();
    if (tid < FBM) {
        float w2 = s_part[0][tid] + s_part[1][tid] + s_part[2][tid] + s_part[3][tid]
                 + s_part[4][tid] + s_part[5][tid] + s_part[6][tid] + s_part[7][tid] + 1e-20f;
        s_winv[tid] = 1.0f / w2;
    }
    __syncthreads();

    const int dq = tid & 63, tg = tid >> 6;
    float4 acc[8];
    #pragma unroll
    for (int i = 0; i < 8; ++i) acc[i] = make_float4(0.f, 0.f, 0.f, 0.f);
    const float* encb = enc + (size_t)b * S_FIX * D + (size_t)dq * 4;
    #pragma unroll 4
    for (int s = 0; s < S_FIX; ++s) {
        float4 ev = *(const float4*)(encb + (size_t)s * D);
        #pragma unroll
        for (int i = 0; i < 8; ++i) {
            float wv = s_w[tg * 8 + i][s];
            acc[i].x = fmaf(wv, ev.x, acc[i].x);
            acc[i].y = fmaf(wv, ev.y, acc[i].y);
            acc[i].z = fmaf(wv, ev.z, acc[i].z);
            acc[i].w = fmaf(wv, ev.w, acc[i].w);
        }
    }
    const float kf = -logf(10000.0f) / (float)D;
    const int d0 = dq * 4;
    const float f0 = __expf(kf * (float)(d0));
    const float f2 = __expf(kf * (float)(d0 + 2));
    float* outb = out + (size_t)b * T * D + (size_t)t0 * D + d0;
    #pragma unroll
    for (int i = 0; i < 8; ++i) {
        const int tl = tg * 8 + i;
        const float inv = s_winv[tl];
        const float tt = (float)(t0 + tl);
        const float a0 = tt * f0, a2 = tt * f2;
        float4 o;
        o.x = acc[i].x * inv + __sinf(a0);
        o.y = acc[i].y * inv + __cosf(a0);
        o.z = acc[i].z * inv + __sinf(a2);
        o.w = acc[i].w * inv + __cosf(a2);
        *(float4*)(outb + (size_t)tl * D) = o;
    }
}

extern "C" void kernel_launch(void* const* d_in, const int* in_sizes, int n_in,
                              void* d_out, int out_size, void* d_ws, size_t ws_size,
                              hipStream_t stream) {
    const float* enc = (const float*)d_in[0];
    const float* dur = (const float*)d_in[1];
    const float* rng = (const float*)d_in[2];
    float* out = (float*)d_out;

    const int S  = S_FIX;
    const int BS = in_sizes[1];
    const int B  = BS / S;
    const int D  = in_sizes[0] / BS;
    const int T  = out_size / (B * D);

    const size_t need = (size_t)B * D * S * sizeof(unsigned short);  // 4 MB

    if (D == D_FIX && (T % BM) == 0 && ws_size >= need) {
        unsigned short* encT = (unsigned short*)d_ws;
        const int nthr = B * (S / 8) * D;
        hipLaunchKernelGGL(transpose_enc_bf16, dim3(nthr / 256), dim3(256), 0, stream,
                           enc, encT);
        hipLaunchKernelGGL(gauss_up_mfma, dim3(B * (T / BM)), dim3(256), 0, stream,
                           dur, rng, encT, out, T);
    } else {
        const int ntiles = T / FBM;
        hipLaunchKernelGGL(gauss_up_f32, dim3(B * ntiles), dim3(BLOCK), 0, stream,
                           enc, dur, rng, out, T, D, ntiles);
    }
}